// Round 1
// baseline (1433.022 us; speedup 1.0000x reference)
//
#include <hip/hip_runtime.h>
#include <math.h>

#define GLN_EPS 0.001f

__device__ __forceinline__ float clipf_(float v) {
    return fminf(fmaxf(v, GLN_EPS), 1.0f - GLN_EPS);
}
__device__ __forceinline__ float logitf_(float p) {
    return logf(p) - log1pf(-p);
}
__device__ __forceinline__ float sigclip_logit(float z) {
    // logit(clip(sigmoid(z))) — replicate reference ops for accuracy parity
    float s = 1.0f / (1.0f + expf(-z));
    s = clipf_(s);
    return logf(s) - log1pf(-s);
}

// ws layout (floats): [0..1023] acc0 (layer0 pre-sigmoid), [1024..1535] acc1,
//                     [1536..1538] gating indices g0,g1,g2 (as int bits)

__global__ __launch_bounds__(256) void gln_prep(
    const float* __restrict__ side,
    const float* __restrict__ N0, const float* __restrict__ O0,
    const float* __restrict__ N1, const float* __restrict__ O1,
    const float* __restrict__ N2, const float* __restrict__ O2,
    float* __restrict__ ws)
{
    const int bid = blockIdx.x, tid = threadIdx.x;
    if (bid == 0) {
        // zero accumulators
        for (int i = tid; i < 1536; i += 256) ws[i] = 0.0f;
        return;
    }
    const float* __restrict__ N = (bid == 1) ? N0 : (bid == 2) ? N1 : N2;
    const float* __restrict__ O = (bid == 1) ? O0 : (bid == 2) ? O1 : O2;

    float p[8];
#pragma unroll
    for (int k = 0; k < 8; ++k) p[k] = 0.0f;

    for (int i = tid; i < 1024; i += 256) {
        const float s = side[i];
        const float4* n4 = reinterpret_cast<const float4*>(N + (size_t)i * 8);
        const float4 a = n4[0];
        const float4 b = n4[1];
        p[0] += s * a.x; p[1] += s * a.y; p[2] += s * a.z; p[3] += s * a.w;
        p[4] += s * b.x; p[5] += s * b.y; p[6] += s * b.z; p[7] += s * b.w;
    }

    __shared__ float red[4][8];
    const int lane = tid & 63, wid = tid >> 6;
#pragma unroll
    for (int k = 0; k < 8; ++k) {
        float v = p[k];
#pragma unroll
        for (int off = 32; off > 0; off >>= 1) v += __shfl_down(v, off);
        if (lane == 0) red[wid][k] = v;
    }
    __syncthreads();
    if (tid == 0) {
        int g = 0;
#pragma unroll
        for (int k = 0; k < 8; ++k) {
            const float d = red[0][k] + red[1][k] + red[2][k] + red[3][k];
            if (d > O[k]) g |= 1 << (7 - k);
        }
        reinterpret_cast<int*>(ws)[1536 + (bid - 1)] = g;
    }
}

// Layer 0 GEMV: acc0[j] = sum_i x[i] * W0[g0][i][j], j in [0,1024)
// x[0] = logit(B0), x[i] = clip(side[i-1])  (logit∘sigmoid == identity)
__global__ __launch_bounds__(256) void gln_gemv0(
    const float* __restrict__ side,
    const float* __restrict__ W0,
    const float* __restrict__ B0,
    float* __restrict__ ws)
{
    const int g = reinterpret_cast<const int*>(ws)[1536];
    const float lb = logitf_(B0[0]);
    const size_t base = (size_t)g * 1025u * 1024u;
    const int col = threadIdx.x * 4;

    float4 acc = make_float4(0.f, 0.f, 0.f, 0.f);
    for (int i = blockIdx.x; i < 1025; i += gridDim.x) {
        const float xi = (i == 0) ? lb : clipf_(side[i - 1]);
        const float4 w = *reinterpret_cast<const float4*>(W0 + base + (size_t)i * 1024u + col);
        acc.x += xi * w.x; acc.y += xi * w.y; acc.z += xi * w.z; acc.w += xi * w.w;
    }
    atomicAdd(&ws[col + 0], acc.x);
    atomicAdd(&ws[col + 1], acc.y);
    atomicAdd(&ws[col + 2], acc.z);
    atomicAdd(&ws[col + 3], acc.w);
}

// Layer 1 GEMV: acc1[j] = sum_i x[i] * W1[g1][i][j], j in [0,512)
// x[0] = logit(B1), x[i] = logit(clip(sigmoid(acc0[i-1])))
__global__ __launch_bounds__(256) void gln_gemv1(
    const float* __restrict__ W1,
    const float* __restrict__ B1,
    float* __restrict__ ws)
{
    const int g = reinterpret_cast<const int*>(ws)[1537];
    const float lb = logitf_(B1[0]);
    const size_t base = (size_t)g * 1025u * 512u;
    const int col = threadIdx.x * 2;

    float2 acc = make_float2(0.f, 0.f);
    for (int i = blockIdx.x; i < 1025; i += gridDim.x) {
        const float xi = (i == 0) ? lb : sigclip_logit(ws[i - 1]);
        const float2 w = *reinterpret_cast<const float2*>(W1 + base + (size_t)i * 512u + col);
        acc.x += xi * w.x; acc.y += xi * w.y;
    }
    atomicAdd(&ws[1024 + col + 0], acc.x);
    atomicAdd(&ws[1024 + col + 1], acc.y);
}

// Layer 2: dot(x, W2[g2][:,0]) over 513 elems -> sigmoid -> clip -> out
__global__ __launch_bounds__(256) void gln_final(
    const float* __restrict__ W2,
    const float* __restrict__ B2,
    float* __restrict__ ws,
    float* __restrict__ out)
{
    const int g = reinterpret_cast<const int*>(ws)[1538];
    const size_t base = (size_t)g * 513u;
    const int tid = threadIdx.x;

    float partial = 0.0f;
    for (int i = tid; i < 513; i += 256) {
        const float xi = (i == 0) ? logitf_(B2[0]) : sigclip_logit(ws[1024 + i - 1]);
        partial += xi * W2[base + i];
    }

    __shared__ float red[4];
#pragma unroll
    for (int off = 32; off > 0; off >>= 1) partial += __shfl_down(partial, off);
    if ((tid & 63) == 0) red[tid >> 6] = partial;
    __syncthreads();
    if (tid == 0) {
        const float z = red[0] + red[1] + red[2] + red[3];
        float o = 1.0f / (1.0f + expf(-z));
        out[0] = clipf_(o);
    }
}

extern "C" void kernel_launch(void* const* d_in, const int* in_sizes, int n_in,
                              void* d_out, int out_size, void* d_ws, size_t ws_size,
                              hipStream_t stream) {
    const float* side = (const float*)d_in[0];
    const float* W0   = (const float*)d_in[1];
    const float* N0   = (const float*)d_in[2];
    const float* O0   = (const float*)d_in[3];
    const float* B0   = (const float*)d_in[4];
    const float* W1   = (const float*)d_in[5];
    const float* N1   = (const float*)d_in[6];
    const float* O1   = (const float*)d_in[7];
    const float* B1   = (const float*)d_in[8];
    const float* W2   = (const float*)d_in[9];
    const float* N2   = (const float*)d_in[10];
    const float* O2   = (const float*)d_in[11];
    const float* B2   = (const float*)d_in[12];
    float* out = (float*)d_out;
    float* ws  = (float*)d_ws;

    hipLaunchKernelGGL(gln_prep,  dim3(4),  dim3(256), 0, stream,
                       side, N0, O0, N1, O1, N2, O2, ws);
    hipLaunchKernelGGL(gln_gemv0, dim3(64), dim3(256), 0, stream, side, W0, B0, ws);
    hipLaunchKernelGGL(gln_gemv1, dim3(64), dim3(256), 0, stream, W1, B1, ws);
    hipLaunchKernelGGL(gln_final, dim3(1),  dim3(256), 0, stream, W2, B2, ws, out);
}